// Round 1
// baseline (21490.427 us; speedup 1.0000x reference)
//
#include <hip/hip_runtime.h>
#include <hip/hip_bf16.h>
#include <math.h>

// Model constants
#define VOCAB 50257
#define CTX 2048
#define DMODEL 1024
#define NHEAD 16
#define NLAYER 8
#define DHEAD 64
#define BATCH 2
#define SEQ 2048
#define NTOK (BATCH * SEQ)   // 4096

// ---------------- embedding: h = wte[x] + wpe[pos] ----------------
__global__ void embed_kernel(const int* __restrict__ x,
                             const float* __restrict__ wte,
                             const float* __restrict__ wpe,
                             float* __restrict__ h) {
    int t = blockIdx.x;            // token 0..4095
    int s = t & (SEQ - 1);         // position in sequence
    int tok = x[t];
    const float* pe = wpe + (long)s * DMODEL;
    const float* te = wte + (long)tok * DMODEL;
    float* ph = h + (long)t * DMODEL;
    for (int d = threadIdx.x; d < DMODEL; d += 256)
        ph[d] = te[d] + pe[d];
}

// ---------------- layernorm ----------------
__device__ inline float wave_sum(float v) {
    for (int off = 32; off; off >>= 1) v += __shfl_xor(v, off);
    return v;
}

__global__ void ln_kernel(const float* __restrict__ in, float* __restrict__ out,
                          const float* __restrict__ g, const float* __restrict__ b,
                          long row_stride) {
    int row = blockIdx.x;
    const float* px = in + (long)row * row_stride;
    float* po = out + (long)row * DMODEL;
    int tid = threadIdx.x;
    int wid = tid >> 6, lane = tid & 63;

    float x[4];
    float s = 0.f;
    #pragma unroll
    for (int i = 0; i < 4; ++i) { x[i] = px[tid + i * 256]; s += x[i]; }
    s = wave_sum(s);
    __shared__ float red[4], red2[4];
    if (lane == 0) red[wid] = s;
    __syncthreads();
    float mean = (red[0] + red[1] + red[2] + red[3]) * (1.0f / DMODEL);

    float s2 = 0.f;
    #pragma unroll
    for (int i = 0; i < 4; ++i) { float d = x[i] - mean; s2 += d * d; }
    s2 = wave_sum(s2);
    if (lane == 0) red2[wid] = s2;
    __syncthreads();
    float var = (red2[0] + red2[1] + red2[2] + red2[3]) * (1.0f / DMODEL);
    float r = 1.0f / sqrtf(var + 1e-5f);
    #pragma unroll
    for (int i = 0; i < 4; ++i) {
        int d = tid + i * 256;
        po[d] = (x[i] - mean) * r * g[d] + b[d];
    }
}

// ---------------- tiled f32 matmul: C = act(A@B + bias) (+R) ----------------
// A[M,K] row-major, B[K,N] row-major. BM=BN=64, BK=32, 256 threads, 4x4/thread.
template<bool GELU, bool RES>
__global__ void mm_kernel(const float* __restrict__ A, const float* __restrict__ Bm,
                          const float* __restrict__ bias, const float* __restrict__ R,
                          float* __restrict__ C, int M, int N, int K) {
    __shared__ float As[32][68];  // [k][m], padded: 68 floats = 272B row (16B aligned)
    __shared__ float Bs[32][68];  // [k][n]
    int tid = threadIdx.x;
    int bm = blockIdx.y * 64, bn = blockIdx.x * 64;
    int tx = tid & 15, ty = tid >> 4;
    float acc[4][4] = {};
    int ka = tid & 31, ra0 = tid >> 5;      // A-load: k = tid%32, rows step 8
    int nb = tid & 63, kb0 = tid >> 6;      // B-load: n = tid%64, k step 4

    for (int k0 = 0; k0 < K; k0 += 32) {
        #pragma unroll
        for (int r = 0; r < 8; ++r)
            As[ka][ra0 + r * 8] = A[(long)(bm + ra0 + r * 8) * K + k0 + ka];
        #pragma unroll
        for (int kk = 0; kk < 8; ++kk)
            Bs[kb0 + kk * 4][nb] = Bm[(long)(k0 + kb0 + kk * 4) * N + bn + nb];
        __syncthreads();
        #pragma unroll
        for (int kk = 0; kk < 32; ++kk) {
            float4 av = *reinterpret_cast<const float4*>(&As[kk][ty * 4]);
            float4 bv = *reinterpret_cast<const float4*>(&Bs[kk][tx * 4]);
            float a[4] = {av.x, av.y, av.z, av.w};
            float b[4] = {bv.x, bv.y, bv.z, bv.w};
            #pragma unroll
            for (int i = 0; i < 4; ++i)
                #pragma unroll
                for (int j = 0; j < 4; ++j)
                    acc[i][j] += a[i] * b[j];
        }
        __syncthreads();
    }
    #pragma unroll
    for (int i = 0; i < 4; ++i) {
        long row = bm + ty * 4 + i;
        #pragma unroll
        for (int j = 0; j < 4; ++j) {
            int col = bn + tx * 4 + j;
            float v = acc[i][j] + bias[col];
            if (GELU) v = 0.5f * v * (1.0f + erff(v * 0.70710678118f));
            if (RES) v += R[row * N + col];
            C[row * N + col] = v;
        }
    }
}

// ---------------- attention (causal, streaming softmax) ----------------
// qkv: [4096, 3072] (q|k|v each 1024). z out: [4096, 1024].
// Block: 256 thr = 4 waves, each wave owns one query row. blockIdx = (b*H+h, qchunk/4)
__global__ void attn_kernel(const float* __restrict__ qkv, float* __restrict__ z) {
    const int bh = blockIdx.x;
    const int b = bh >> 4, hh = bh & 15;
    const int qbase = blockIdx.y * 4;
    const int tid = threadIdx.x;
    const int w = tid >> 6, lane = tid & 63;
    __shared__ float Ks[64][65];
    __shared__ float Vs[64][65];
    __shared__ float qs[4][64];
    __shared__ float ps[4][64];

    const long base = (long)b * SEQ * 3072;
    const int hofs = hh * 64;
    const int q = qbase + w;

    qs[w][lane] = qkv[base + (long)q * 3072 + hofs + lane];
    __syncthreads();

    float m = -INFINITY, lsum = 0.f, acc = 0.f;
    const int nch = qbase / 64 + 1;   // rows in a block never straddle a 64-chunk

    for (int c = 0; c < nch; ++c) {
        int dd = tid & 63, r0 = tid >> 6;
        #pragma unroll 4
        for (int r = r0; r < 64; r += 4) {
            long krow = base + (long)(c * 64 + r) * 3072 + hofs + dd;
            Ks[r][dd] = qkv[krow + 1024];
            Vs[r][dd] = qkv[krow + 2048];
        }
        __syncthreads();

        int key = c * 64 + lane;
        float dot = 0.f;
        #pragma unroll 16
        for (int d = 0; d < 64; ++d) dot += qs[w][d] * Ks[lane][d];
        float val = (key <= q) ? dot * 0.125f : -INFINITY;

        float mc = val;
        for (int off = 32; off; off >>= 1) mc = fmaxf(mc, __shfl_xor(mc, off));
        float mnew = fmaxf(m, mc);
        float p = expf(val - mnew);          // -inf -> 0
        float psum = p;
        for (int off = 32; off; off >>= 1) psum += __shfl_xor(psum, off);
        float sc = expf(m - mnew);           // first chunk: exp(-inf-finite)=0
        lsum = lsum * sc + psum;
        acc *= sc;
        ps[w][lane] = p;
        __syncthreads();
        #pragma unroll 16
        for (int j = 0; j < 64; ++j) acc += ps[w][j] * Vs[j][lane];
        __syncthreads();
        m = mnew;
    }
    z[((long)b * SEQ + q) * DMODEL + hofs + lane] = acc / lsum;
}

// ---------------- head: out[b, v] = hl[b,:] @ W[:, v] ----------------
__global__ void head_kernel(const float* __restrict__ hl, const float* __restrict__ W,
                            float* __restrict__ out) {
    __shared__ float hs[2 * DMODEL];
    int tid = threadIdx.x;
    #pragma unroll
    for (int i = 0; i < 8; ++i) hs[tid + i * 256] = hl[tid + i * 256];
    __syncthreads();
    int v = blockIdx.x * 256 + tid;
    if (v >= VOCAB) return;
    float a0 = 0.f, a1 = 0.f;
    for (int d = 0; d < DMODEL; ++d) {
        float wv = W[(long)d * VOCAB + v];
        a0 += hs[d] * wv;
        a1 += hs[DMODEL + d] * wv;
    }
    out[v] = a0;
    out[VOCAB + v] = a1;
}

extern "C" void kernel_launch(void* const* d_in, const int* in_sizes, int n_in,
                              void* d_out, int out_size, void* d_ws, size_t ws_size,
                              hipStream_t stream) {
    const int*   x      = (const int*)  d_in[0];
    const float* wte    = (const float*)d_in[1];
    const float* wpe    = (const float*)d_in[2];
    const float* ln1_g  = (const float*)d_in[3];
    const float* ln1_b  = (const float*)d_in[4];
    const float* w_qkv  = (const float*)d_in[5];
    const float* b_qkv  = (const float*)d_in[6];
    const float* w_proj = (const float*)d_in[7];
    const float* b_proj = (const float*)d_in[8];
    const float* ln2_g  = (const float*)d_in[9];
    const float* ln2_b  = (const float*)d_in[10];
    const float* w_fc   = (const float*)d_in[11];
    const float* b_fc   = (const float*)d_in[12];
    const float* w_cp   = (const float*)d_in[13];
    const float* b_cp   = (const float*)d_in[14];
    const float* lnf_g  = (const float*)d_in[15];
    const float* lnf_b  = (const float*)d_in[16];
    const float* w_head = (const float*)d_in[17];
    float* out = (float*)d_out;

    float* ws  = (float*)d_ws;
    float* h   = ws;                          // 4096*1024
    float* y   = h   + (long)NTOK * DMODEL;   // 4096*1024
    float* qkv = y   + (long)NTOK * DMODEL;   // 4096*3072
    float* fc  = qkv + (long)NTOK * 3 * DMODEL; // 4096*4096
    float* hl  = fc  + (long)NTOK * 4 * DMODEL; // 2*1024

    embed_kernel<<<NTOK, 256, 0, stream>>>(x, wte, wpe, h);

    for (int l = 0; l < NLAYER; ++l) {
        ln_kernel<<<NTOK, 256, 0, stream>>>(h, y, ln1_g + l * DMODEL, ln1_b + l * DMODEL, DMODEL);
        mm_kernel<false, false><<<dim3(3072 / 64, NTOK / 64), 256, 0, stream>>>(
            y, w_qkv + (long)l * DMODEL * 3072, b_qkv + l * 3072, nullptr, qkv,
            NTOK, 3072, DMODEL);
        attn_kernel<<<dim3(BATCH * NHEAD, SEQ / 4), 256, 0, stream>>>(qkv, y);
        mm_kernel<false, true><<<dim3(DMODEL / 64, NTOK / 64), 256, 0, stream>>>(
            y, w_proj + (long)l * DMODEL * DMODEL, b_proj + l * DMODEL, h, h,
            NTOK, DMODEL, DMODEL);
        ln_kernel<<<NTOK, 256, 0, stream>>>(h, y, ln2_g + l * DMODEL, ln2_b + l * DMODEL, DMODEL);
        mm_kernel<true, false><<<dim3(4096 / 64, NTOK / 64), 256, 0, stream>>>(
            y, w_fc + (long)l * DMODEL * 4096, b_fc + l * 4096, nullptr, fc,
            NTOK, 4096, DMODEL);
        mm_kernel<false, true><<<dim3(DMODEL / 64, NTOK / 64), 256, 0, stream>>>(
            fc, w_cp + (long)l * 4096 * DMODEL, b_cp + l * DMODEL, h, h,
            NTOK, DMODEL, 4096);
    }

    // final LN on last position of each batch row: tokens S-1 and 2S-1
    ln_kernel<<<BATCH, 256, 0, stream>>>(h + (long)(SEQ - 1) * DMODEL, hl,
                                         lnf_g, lnf_b, (long)SEQ * DMODEL);
    head_kernel<<<(VOCAB + 255) / 256, 256, 0, stream>>>(hl, w_head, out);
}

// Round 2
// 11137.331 us; speedup vs baseline: 1.9296x; 1.9296x over previous
//
#include <hip/hip_runtime.h>
#include <hip/hip_bf16.h>
#include <math.h>

// Model constants
#define VOCAB 50257
#define CTX 2048
#define DMODEL 1024
#define NHEAD 16
#define NLAYER 8
#define DHEAD 64
#define BATCH 2
#define SEQ 2048
#define NTOK (BATCH * SEQ)   // 4096

typedef __bf16 bf16x8 __attribute__((ext_vector_type(8)));
typedef float  f32x4  __attribute__((ext_vector_type(4)));

__device__ inline void gl_lds16(const void* g, void* l) {
    __builtin_amdgcn_global_load_lds(
        (const __attribute__((address_space(1))) unsigned int*)g,
        (__attribute__((address_space(3))) unsigned int*)l, 16, 0, 0);
}

// ---------------- embedding: h = wte[x] + wpe[pos] ----------------
__global__ void embed_kernel(const int* __restrict__ x,
                             const float* __restrict__ wte,
                             const float* __restrict__ wpe,
                             float* __restrict__ h) {
    int t = blockIdx.x;
    int s = t & (SEQ - 1);
    int tok = x[t];
    const float* pe = wpe + (long)s * DMODEL;
    const float* te = wte + (long)tok * DMODEL;
    float* ph = h + (long)t * DMODEL;
    for (int d = threadIdx.x; d < DMODEL; d += 256)
        ph[d] = te[d] + pe[d];
}

// ---------------- layernorm (templated output dtype) ----------------
__device__ inline float wave_sum(float v) {
    for (int off = 32; off; off >>= 1) v += __shfl_xor(v, off);
    return v;
}
__device__ inline void st_val(float* p, float v) { *p = v; }
__device__ inline void st_val(__hip_bfloat16* p, float v) { *p = __float2bfloat16(v); }

template<typename OT>
__global__ void ln_kernel(const float* __restrict__ in, OT* __restrict__ out,
                          const float* __restrict__ g, const float* __restrict__ b,
                          long row_stride) {
    int row = blockIdx.x;
    const float* px = in + (long)row * row_stride;
    OT* po = out + (long)row * DMODEL;
    int tid = threadIdx.x;
    int wid = tid >> 6, lane = tid & 63;

    float x[4];
    float s = 0.f;
    #pragma unroll
    for (int i = 0; i < 4; ++i) { x[i] = px[tid + i * 256]; s += x[i]; }
    s = wave_sum(s);
    __shared__ float red[4], red2[4];
    if (lane == 0) red[wid] = s;
    __syncthreads();
    float mean = (red[0] + red[1] + red[2] + red[3]) * (1.0f / DMODEL);

    float s2 = 0.f;
    #pragma unroll
    for (int i = 0; i < 4; ++i) { float d = x[i] - mean; s2 += d * d; }
    s2 = wave_sum(s2);
    if (lane == 0) red2[wid] = s2;
    __syncthreads();
    float var = (red2[0] + red2[1] + red2[2] + red2[3]) * (1.0f / DMODEL);
    float r = 1.0f / sqrtf(var + 1e-5f);
    #pragma unroll
    for (int i = 0; i < 4; ++i) {
        int d = tid + i * 256;
        st_val(po + d, (x[i] - mean) * r * g[d] + b[d]);
    }
}

// ------------- transpose+convert: W f32 [K][N] -> WT bf16 [N][K] -------------
__global__ void convT_kernel(const float* __restrict__ W,
                             __hip_bfloat16* __restrict__ WT, int K, int N) {
    __shared__ float t[32][33];
    int n0 = blockIdx.x * 32, k0 = blockIdx.y * 32;
    int tx = threadIdx.x & 31, ty = threadIdx.x >> 5;   // 32 x 8
    #pragma unroll
    for (int i = 0; i < 4; ++i)
        t[ty + i * 8][tx] = W[(long)(k0 + ty + i * 8) * N + n0 + tx];
    __syncthreads();
    #pragma unroll
    for (int i = 0; i < 4; ++i)
        WT[(long)(n0 + ty + i * 8) * K + k0 + tx] = __float2bfloat16(t[tx][ty + i * 8]);
}

// ---------------- bf16 MFMA GEMM: C = epi(A @ BT^T + bias [+R]) ----------------
// A [M][K] bf16 row-major, BT [N][K] bf16 row-major (i.e. B transposed).
// 128x128 tile, BK=32, 256 threads (4 waves, 2x2 of 64x64), 16x16x32 MFMA.
// EPI: 0 = f32 +bias; 1 = f32 +bias+R; 2 = bf16 gelu(x+bias)
template<int EPI>
__global__ __launch_bounds__(256)
void mm_mfma(const unsigned short* __restrict__ A,
             const unsigned short* __restrict__ BT,
             const float* __restrict__ bias, const float* __restrict__ R,
             void* __restrict__ Cout, int M, int N, int K) {
    __shared__ unsigned short As[128 * 32];
    __shared__ unsigned short Bs[128 * 32];
    const int tid = threadIdx.x;
    const int w = tid >> 6, lane = tid & 63;
    const int bm = blockIdx.y * 128, bn = blockIdx.x * 128;
    const int wr = (w >> 1) * 64, wc = (w & 1) * 64;

    f32x4 acc[4][4];
    #pragma unroll
    for (int m = 0; m < 4; ++m)
        #pragma unroll
        for (int n = 0; n < 4; ++n)
            acc[m][n] = (f32x4){0.f, 0.f, 0.f, 0.f};

    const int lrow = lane >> 2;           // 0..15
    const int lcol = (lane & 3) * 8;      // 0,8,16,24 (elements)
    // wave w stages A rows [bm + w*32, +32) and BT rows [bn + w*32, +32)
    const unsigned short* gA = A + (long)(bm + w * 32 + lrow) * K + lcol;
    const unsigned short* gB = BT + (long)(bn + w * 32 + lrow) * K + lcol;
    unsigned short* lA = &As[(w * 32) * 32];
    unsigned short* lB = &Bs[(w * 32) * 32];

    for (int k0 = 0; k0 < K; k0 += 32) {
        gl_lds16(gA + k0,          lA);
        gl_lds16(gA + k0 + 16 * K, lA + 16 * 32);
        gl_lds16(gB + k0,          lB);
        gl_lds16(gB + k0 + 16 * K, lB + 16 * 32);
        __syncthreads();   // compiler emits vmcnt(0) drain + barrier

        bf16x8 a[4], b[4];
        #pragma unroll
        for (int m = 0; m < 4; ++m)
            a[m] = *(const bf16x8*)&As[(wr + m * 16 + (lane & 15)) * 32 + (lane >> 4) * 8];
        #pragma unroll
        for (int n = 0; n < 4; ++n)
            b[n] = *(const bf16x8*)&Bs[(wc + n * 16 + (lane & 15)) * 32 + (lane >> 4) * 8];
        #pragma unroll
        for (int m = 0; m < 4; ++m)
            #pragma unroll
            for (int n = 0; n < 4; ++n)
                acc[m][n] = __builtin_amdgcn_mfma_f32_16x16x32_bf16(a[m], b[n], acc[m][n], 0, 0, 0);
        __syncthreads();
    }

    const int r0 = (lane >> 4) * 4, cc = lane & 15;
    #pragma unroll
    for (int m = 0; m < 4; ++m) {
        #pragma unroll
        for (int n = 0; n < 4; ++n) {
            long col = bn + wc + n * 16 + cc;
            float bv = bias[col];
            #pragma unroll
            for (int r = 0; r < 4; ++r) {
                long row = bm + wr + m * 16 + r0 + r;
                float v = acc[m][n][r] + bv;
                if (EPI == 1) {
                    v += R[row * N + col];
                    ((float*)Cout)[row * N + col] = v;
                } else if (EPI == 2) {
                    v = 0.5f * v * (1.0f + erff(v * 0.70710678118f));
                    ((__hip_bfloat16*)Cout)[row * N + col] = __float2bfloat16(v);
                } else {
                    ((float*)Cout)[row * N + col] = v;
                }
            }
        }
    }
}

// ---------------- attention (causal, streaming softmax), bf16 z out ----------------
__global__ void attn_kernel(const float* __restrict__ qkv, __hip_bfloat16* __restrict__ z) {
    const int bh = blockIdx.x;
    const int b = bh >> 4, hh = bh & 15;
    const int qbase = blockIdx.y * 4;
    const int tid = threadIdx.x;
    const int w = tid >> 6, lane = tid & 63;
    __shared__ float Ks[64][65];
    __shared__ float Vs[64][65];
    __shared__ float qs[4][64];
    __shared__ float ps[4][64];

    const long base = (long)b * SEQ * 3072;
    const int hofs = hh * 64;
    const int q = qbase + w;

    qs[w][lane] = qkv[base + (long)q * 3072 + hofs + lane];
    __syncthreads();

    float m = -INFINITY, lsum = 0.f, acc = 0.f;
    const int nch = qbase / 64 + 1;

    for (int c = 0; c < nch; ++c) {
        int dd = tid & 63, r0 = tid >> 6;
        #pragma unroll 4
        for (int r = r0; r < 64; r += 4) {
            long krow = base + (long)(c * 64 + r) * 3072 + hofs + dd;
            Ks[r][dd] = qkv[krow + 1024];
            Vs[r][dd] = qkv[krow + 2048];
        }
        __syncthreads();

        int key = c * 64 + lane;
        float dot = 0.f;
        #pragma unroll 16
        for (int d = 0; d < 64; ++d) dot += qs[w][d] * Ks[lane][d];
        float val = (key <= q) ? dot * 0.125f : -INFINITY;

        float mc = val;
        for (int off = 32; off; off >>= 1) mc = fmaxf(mc, __shfl_xor(mc, off));
        float mnew = fmaxf(m, mc);
        float p = expf(val - mnew);
        float psum = p;
        for (int off = 32; off; off >>= 1) psum += __shfl_xor(psum, off);
        float sc = expf(m - mnew);
        lsum = lsum * sc + psum;
        acc *= sc;
        ps[w][lane] = p;
        __syncthreads();
        #pragma unroll 16
        for (int j = 0; j < 64; ++j) acc += ps[w][j] * Vs[j][lane];
        __syncthreads();
        m = mnew;
    }
    z[((long)b * SEQ + q) * DMODEL + hofs + lane] = __float2bfloat16(acc / lsum);
}

// ---------------- head: out[b, v] = hl[b,:] @ W[:, v] ----------------
__global__ void head_kernel(const float* __restrict__ hl, const float* __restrict__ W,
                            float* __restrict__ out) {
    __shared__ float hs[2 * DMODEL];
    int tid = threadIdx.x;
    #pragma unroll
    for (int i = 0; i < 8; ++i) hs[tid + i * 256] = hl[tid + i * 256];
    __syncthreads();
    int v = blockIdx.x * 256 + tid;
    if (v >= VOCAB) return;
    float a0 = 0.f, a1 = 0.f;
    for (int d = 0; d < DMODEL; ++d) {
        float wv = W[(long)d * VOCAB + v];
        a0 += hs[d] * wv;
        a1 += hs[DMODEL + d] * wv;
    }
    out[v] = a0;
    out[VOCAB + v] = a1;
}

extern "C" void kernel_launch(void* const* d_in, const int* in_sizes, int n_in,
                              void* d_out, int out_size, void* d_ws, size_t ws_size,
                              hipStream_t stream) {
    const int*   x      = (const int*)  d_in[0];
    const float* wte    = (const float*)d_in[1];
    const float* wpe    = (const float*)d_in[2];
    const float* ln1_g  = (const float*)d_in[3];
    const float* ln1_b  = (const float*)d_in[4];
    const float* w_qkv  = (const float*)d_in[5];
    const float* b_qkv  = (const float*)d_in[6];
    const float* w_proj = (const float*)d_in[7];
    const float* b_proj = (const float*)d_in[8];
    const float* ln2_g  = (const float*)d_in[9];
    const float* ln2_b  = (const float*)d_in[10];
    const float* w_fc   = (const float*)d_in[11];
    const float* b_fc   = (const float*)d_in[12];
    const float* w_cp   = (const float*)d_in[13];
    const float* b_cp   = (const float*)d_in[14];
    const float* lnf_g  = (const float*)d_in[15];
    const float* lnf_b  = (const float*)d_in[16];
    const float* w_head = (const float*)d_in[17];
    float* out = (float*)d_out;

    char* ws = (char*)d_ws;
    float*          h     = (float*)ws;                                // 16 MB
    float*          qkv   = (float*)(ws + (16L << 20));                // 48 MB
    __hip_bfloat16* y_bf  = (__hip_bfloat16*)(ws + (64L << 20));       // 8 MB
    __hip_bfloat16* z_bf  = (__hip_bfloat16*)(ws + (72L << 20));       // 8 MB
    __hip_bfloat16* fc_bf = (__hip_bfloat16*)(ws + (80L << 20));       // 32 MB
    __hip_bfloat16* wT    = (__hip_bfloat16*)(ws + (112L << 20));      // 8.5 MB
    float*          hl    = (float*)(ws + (121L << 20));               // 8 KB

    embed_kernel<<<NTOK, 256, 0, stream>>>(x, wte, wpe, h);

    for (int l = 0; l < NLAYER; ++l) {
        ln_kernel<__hip_bfloat16><<<NTOK, 256, 0, stream>>>(
            h, y_bf, ln1_g + l * DMODEL, ln1_b + l * DMODEL, DMODEL);

        convT_kernel<<<dim3(3072 / 32, 1024 / 32), 256, 0, stream>>>(
            w_qkv + (long)l * DMODEL * 3072, wT, 1024, 3072);
        mm_mfma<0><<<dim3(3072 / 128, NTOK / 128), 256, 0, stream>>>(
            (const unsigned short*)y_bf, (const unsigned short*)wT,
            b_qkv + l * 3072, nullptr, qkv, NTOK, 3072, 1024);

        attn_kernel<<<dim3(BATCH * NHEAD, SEQ / 4), 256, 0, stream>>>(qkv, z_bf);

        convT_kernel<<<dim3(1024 / 32, 1024 / 32), 256, 0, stream>>>(
            w_proj + (long)l * DMODEL * DMODEL, wT, 1024, 1024);
        mm_mfma<1><<<dim3(1024 / 128, NTOK / 128), 256, 0, stream>>>(
            (const unsigned short*)z_bf, (const unsigned short*)wT,
            b_proj + l * DMODEL, h, h, NTOK, 1024, 1024);

        ln_kernel<__hip_bfloat16><<<NTOK, 256, 0, stream>>>(
            h, y_bf, ln2_g + l * DMODEL, ln2_b + l * DMODEL, DMODEL);

        convT_kernel<<<dim3(4096 / 32, 1024 / 32), 256, 0, stream>>>(
            w_fc + (long)l * DMODEL * 4096, wT, 1024, 4096);
        mm_mfma<2><<<dim3(4096 / 128, NTOK / 128), 256, 0, stream>>>(
            (const unsigned short*)y_bf, (const unsigned short*)wT,
            b_fc + l * 4096, nullptr, fc_bf, NTOK, 4096, 1024);

        convT_kernel<<<dim3(1024 / 32, 4096 / 32), 256, 0, stream>>>(
            w_cp + (long)l * 4096 * DMODEL, wT, 4096, 1024);
        mm_mfma<1><<<dim3(1024 / 128, NTOK / 128), 256, 0, stream>>>(
            (const unsigned short*)fc_bf, (const unsigned short*)wT,
            b_cp + l * DMODEL, h, h, NTOK, 1024, 4096);
    }

    ln_kernel<float><<<BATCH, 256, 0, stream>>>(h + (long)(SEQ - 1) * DMODEL, hl,
                                                lnf_g, lnf_b, (long)SEQ * DMODEL);
    head_kernel<<<(VOCAB + 255) / 256, 256, 0, stream>>>(hl, w_head, out);
}

// Round 3
// 2915.080 us; speedup vs baseline: 7.3722x; 3.8206x over previous
//
#include <hip/hip_runtime.h>
#include <hip/hip_bf16.h>
#include <math.h>

// Model constants
#define VOCAB 50257
#define CTX 2048
#define DMODEL 1024
#define NHEAD 16
#define NLAYER 8
#define DHEAD 64
#define BATCH 2
#define SEQ 2048
#define NTOK (BATCH * SEQ)   // 4096

typedef __bf16 bf16x8 __attribute__((ext_vector_type(8)));
typedef float  f32x4  __attribute__((ext_vector_type(4)));
typedef unsigned short ushort4v __attribute__((ext_vector_type(4)));

__device__ inline void gl_lds16(const void* g, void* l) {
    __builtin_amdgcn_global_load_lds(
        (const __attribute__((address_space(1))) unsigned int*)g,
        (__attribute__((address_space(3))) unsigned int*)l, 16, 0, 0);
}

__device__ inline unsigned short f2bs(float v) {
    __hip_bfloat16 t = __float2bfloat16(v);
    return *(unsigned short*)&t;
}

// ---------------- embedding ----------------
__global__ void embed_kernel(const int* __restrict__ x,
                             const float* __restrict__ wte,
                             const float* __restrict__ wpe,
                             float* __restrict__ h) {
    int t = blockIdx.x;
    int s = t & (SEQ - 1);
    int tok = x[t];
    const float* pe = wpe + (long)s * DMODEL;
    const float* te = wte + (long)tok * DMODEL;
    float* ph = h + (long)t * DMODEL;
    for (int d = threadIdx.x; d < DMODEL; d += 256)
        ph[d] = te[d] + pe[d];
}

// ---------------- layernorm ----------------
__device__ inline float wave_sum(float v) {
    for (int off = 32; off; off >>= 1) v += __shfl_xor(v, off);
    return v;
}
__device__ inline void st_val(float* p, float v) { *p = v; }
__device__ inline void st_val(__hip_bfloat16* p, float v) { *p = __float2bfloat16(v); }

template<typename OT>
__global__ void ln_kernel(const float* __restrict__ in, OT* __restrict__ out,
                          const float* __restrict__ g, const float* __restrict__ b,
                          long row_stride) {
    int row = blockIdx.x;
    const float* px = in + (long)row * row_stride;
    OT* po = out + (long)row * DMODEL;
    int tid = threadIdx.x;
    int wid = tid >> 6, lane = tid & 63;

    float x[4];
    float s = 0.f;
    #pragma unroll
    for (int i = 0; i < 4; ++i) { x[i] = px[tid + i * 256]; s += x[i]; }
    s = wave_sum(s);
    __shared__ float red[4], red2[4];
    if (lane == 0) red[wid] = s;
    __syncthreads();
    float mean = (red[0] + red[1] + red[2] + red[3]) * (1.0f / DMODEL);

    float s2 = 0.f;
    #pragma unroll
    for (int i = 0; i < 4; ++i) { float d = x[i] - mean; s2 += d * d; }
    s2 = wave_sum(s2);
    if (lane == 0) red2[wid] = s2;
    __syncthreads();
    float var = (red2[0] + red2[1] + red2[2] + red2[3]) * (1.0f / DMODEL);
    float r = 1.0f / sqrtf(var + 1e-5f);
    #pragma unroll
    for (int i = 0; i < 4; ++i) {
        int d = tid + i * 256;
        st_val(po + d, (x[i] - mean) * r * g[d] + b[d]);
    }
}

// ------------- transpose+convert: W f32 [K][N] -> WT bf16 [N][K] -------------
__global__ void convT_kernel(const float* __restrict__ W,
                             __hip_bfloat16* __restrict__ WT, int K, int N) {
    __shared__ float t[32][33];
    int n0 = blockIdx.x * 32, k0 = blockIdx.y * 32;
    int tx = threadIdx.x & 31, ty = threadIdx.x >> 5;
    #pragma unroll
    for (int i = 0; i < 4; ++i)
        t[ty + i * 8][tx] = W[(long)(k0 + ty + i * 8) * N + n0 + tx];
    __syncthreads();
    #pragma unroll
    for (int i = 0; i < 4; ++i)
        WT[(long)(n0 + ty + i * 8) * K + k0 + tx] = __float2bfloat16(t[tx][ty + i * 8]);
}

// ---------------- bf16 MFMA GEMM ----------------
// A [M][K] bf16, BT [N][K] bf16. 128x128 tile, BK=32, 4 waves.
// EPI: 1 = f32 +bias+R; 2 = bf16 gelu(x+bias); 3 = qkv scatter to qB|kB|vT
template<int EPI>
__global__ __launch_bounds__(256)
void mm_mfma(const unsigned short* __restrict__ A,
             const unsigned short* __restrict__ BT,
             const float* __restrict__ bias, const float* __restrict__ R,
             void* __restrict__ Cout, int M, int N, int K) {
    __shared__ unsigned short As[128 * 32];
    __shared__ unsigned short Bs[128 * 32];
    const int tid = threadIdx.x;
    const int w = tid >> 6, lane = tid & 63;
    const int bm = blockIdx.y * 128, bn = blockIdx.x * 128;
    const int wr = (w >> 1) * 64, wc = (w & 1) * 64;

    f32x4 acc[4][4];
    #pragma unroll
    for (int m = 0; m < 4; ++m)
        #pragma unroll
        for (int n = 0; n < 4; ++n)
            acc[m][n] = (f32x4){0.f, 0.f, 0.f, 0.f};

    const int lrow = lane >> 2;
    const int lcol = (lane & 3) * 8;
    const unsigned short* gA = A + (long)(bm + w * 32 + lrow) * K + lcol;
    const unsigned short* gB = BT + (long)(bn + w * 32 + lrow) * K + lcol;
    unsigned short* lA = &As[(w * 32) * 32];
    unsigned short* lB = &Bs[(w * 32) * 32];

    for (int k0 = 0; k0 < K; k0 += 32) {
        gl_lds16(gA + k0,          lA);
        gl_lds16(gA + k0 + 16 * K, lA + 16 * 32);
        gl_lds16(gB + k0,          lB);
        gl_lds16(gB + k0 + 16 * K, lB + 16 * 32);
        __syncthreads();

        bf16x8 a[4], b[4];
        #pragma unroll
        for (int m = 0; m < 4; ++m)
            a[m] = *(const bf16x8*)&As[(wr + m * 16 + (lane & 15)) * 32 + (lane >> 4) * 8];
        #pragma unroll
        for (int n = 0; n < 4; ++n)
            b[n] = *(const bf16x8*)&Bs[(wc + n * 16 + (lane & 15)) * 32 + (lane >> 4) * 8];
        #pragma unroll
        for (int m = 0; m < 4; ++m)
            #pragma unroll
            for (int n = 0; n < 4; ++n)
                acc[m][n] = __builtin_amdgcn_mfma_f32_16x16x32_bf16(a[m], b[n], acc[m][n], 0, 0, 0);
        __syncthreads();
    }

    const int r0 = (lane >> 4) * 4, cc = lane & 15;
    #pragma unroll
    for (int n = 0; n < 4; ++n) {
        int colb = bn + wc + n * 16;
        float bv = bias[colb + cc];
        #pragma unroll
        for (int m = 0; m < 4; ++m) {
            int rowb = bm + wr + m * 16 + r0;
            if (EPI == 3) {
                // qkv scatter: Cout = qB base; kB at +4M elems, vT at +8M elems
                unsigned short* qkvB = (unsigned short*)Cout;
                int which = colb >> 10, hh = (colb & 1023) >> 6, dbase = colb & 63;
                int b_ = rowb >> 11, s_ = rowb & 2047;
                long bh2 = b_ * 16 + hh;
                float v[4];
                #pragma unroll
                for (int r = 0; r < 4; ++r) v[r] = acc[m][n][r] + bv;
                if (which == 2) {
                    ushort4v pk;
                    #pragma unroll
                    for (int r = 0; r < 4; ++r) pk[r] = f2bs(v[r]);
                    *(ushort4v*)&qkvB[8388608L + (bh2 * 64 + dbase + cc) * 2048 + s_] = pk;
                } else {
                    unsigned short* dst = qkvB + (long)which * 4194304L +
                                          (bh2 * 2048 + s_) * 64 + dbase + cc;
                    #pragma unroll
                    for (int r = 0; r < 4; ++r) dst[r * 64] = f2bs(v[r]);
                }
            } else {
                #pragma unroll
                for (int r = 0; r < 4; ++r) {
                    long row = rowb + r, col = colb + cc;
                    float v = acc[m][n][r] + bv;
                    if (EPI == 1) {
                        v += R[row * N + col];
                        ((float*)Cout)[row * N + col] = v;
                    } else {
                        v = 0.5f * v * (1.0f + erff(v * 0.70710678118f));
                        ((__hip_bfloat16*)Cout)[row * N + col] = __float2bfloat16(v);
                    }
                }
            }
        }
    }
}

// ---------------- MFMA flash attention ----------------
// qB,kB: [bh][s][64] bf16. vT: [bh][64][s] bf16. z: [b][s][1024] bf16.
// Block: 256 thr = 4 waves; 64 q-rows per block (16/wave); KV chunks of 64.
__global__ __launch_bounds__(256)
void attn_mfma(const unsigned short* __restrict__ qB,
               const unsigned short* __restrict__ kB,
               const unsigned short* __restrict__ vT,
               __hip_bfloat16* __restrict__ z) {
    const int bh = blockIdx.x;
    const int qb = blockIdx.y * 64;
    const int tid = threadIdx.x, w = tid >> 6, lane = tid & 63;
    const int arow = lane & 15, kg = lane >> 4;     // fragment row / k-group
    __shared__ unsigned short Ks[64 * 64];          // [key][d], chunk-swizzled
    __shared__ unsigned short Vs[64 * 64];          // [d][key], chunk-swizzled
    __shared__ unsigned short Ps[4][16 * 64];       // per-wave P, chunk-swizzled

    const long kvbase = (long)bh * (2048 * 64);

    bf16x8 qa[2];
    {
        const unsigned short* q0 = qB + kvbase + (long)(qb + w * 16 + arow) * 64 + kg * 8;
        qa[0] = *(const bf16x8*)(q0);
        qa[1] = *(const bf16x8*)(q0 + 32);
    }

    f32x4 po[4];
    float mrow[4], lrow[4];
    #pragma unroll
    for (int i = 0; i < 4; ++i) {
        po[i] = (f32x4){0.f, 0.f, 0.f, 0.f};
        mrow[i] = -1e30f; lrow[i] = 0.f;
    }

    // staging: each wave stages 16 rows of Ks and Vs via gl_lds16, source
    // pre-swizzled (chunk ^= row&7) so swizzled reads land right (rule #21).
    const int srow = lane >> 3;                 // 0..7
    const int schunk = (lane & 7) ^ srow;       // inverse-swizzled source chunk
    const int cmax = qb >> 6;

    for (int c = 0; c <= cmax; ++c) {
        {
            const unsigned short* ks0 = kB + kvbase + (long)(c * 64 + w * 16 + srow) * 64 + schunk * 8;
            const unsigned short* vs0 = vT + kvbase + (long)(w * 16 + srow) * 2048 + c * 64 + schunk * 8;
            gl_lds16(ks0,            &Ks[(w * 16) * 64]);
            gl_lds16(ks0 + 8 * 64,   &Ks[(w * 16 + 8) * 64]);
            gl_lds16(vs0,            &Vs[(w * 16) * 64]);
            gl_lds16(vs0 + 8 * 2048, &Vs[(w * 16 + 8) * 64]);
        }
        __syncthreads();

        // S = Q @ K^T  (per wave: 16 rows x 64 keys)
        f32x4 s[4];
        #pragma unroll
        for (int n = 0; n < 4; ++n) {
            s[n] = (f32x4){0.f, 0.f, 0.f, 0.f};
            int row = n * 16 + arow, sw = row & 7;
            bf16x8 kb0 = *(const bf16x8*)&Ks[row * 64 + (kg ^ sw) * 8];
            bf16x8 kb1 = *(const bf16x8*)&Ks[row * 64 + ((4 + kg) ^ sw) * 8];
            s[n] = __builtin_amdgcn_mfma_f32_16x16x32_bf16(qa[0], kb0, s[n], 0, 0, 0);
            s[n] = __builtin_amdgcn_mfma_f32_16x16x32_bf16(qa[1], kb1, s[n], 0, 0, 0);
        }

        // scale + causal mask (only diagonal chunk)
        const bool diag = (c == cmax);
        #pragma unroll
        for (int n = 0; n < 4; ++n)
            #pragma unroll
            for (int r = 0; r < 4; ++r) {
                float v = s[n][r] * 0.125f;
                if (diag) {
                    int key = c * 64 + n * 16 + arow;
                    int qrow = qb + w * 16 + kg * 4 + r;
                    if (key > qrow) v = -1e30f;
                }
                s[n][r] = v;
            }

        // online softmax (16-lane butterfly per row)
        #pragma unroll
        for (int r = 0; r < 4; ++r) {
            float rm = fmaxf(fmaxf(s[0][r], s[1][r]), fmaxf(s[2][r], s[3][r]));
            #pragma unroll
            for (int off = 1; off < 16; off <<= 1)
                rm = fmaxf(rm, __shfl_xor(rm, off));
            float mnew = fmaxf(mrow[r], rm);
            float esc = expf(mrow[r] - mnew);
            float rs = 0.f;
            #pragma unroll
            for (int n = 0; n < 4; ++n) {
                float p = expf(s[n][r] - mnew);
                s[n][r] = p;
                rs += p;
            }
            #pragma unroll
            for (int off = 1; off < 16; off <<= 1)
                rs += __shfl_xor(rs, off);
            lrow[r] = lrow[r] * esc + rs;
            #pragma unroll
            for (int dt = 0; dt < 4; ++dt) po[dt][r] *= esc;
            mrow[r] = mnew;
        }

        // write P (bf16) to wave-private LDS tile, swizzled
        #pragma unroll
        for (int n = 0; n < 4; ++n) {
            int col = n * 16 + arow;
            int chunk = col >> 3, cw = col & 7;
            #pragma unroll
            for (int r = 0; r < 4; ++r) {
                int row = kg * 4 + r;
                Ps[w][row * 64 + ((chunk ^ (row & 7)) * 8 + cw)] = f2bs(s[n][r]);
            }
        }

        // O += P @ V
        bf16x8 pa[2];
        #pragma unroll
        for (int ks = 0; ks < 2; ++ks)
            pa[ks] = *(const bf16x8*)&Ps[w][arow * 64 + (((ks * 4 + kg) ^ (arow & 7)) * 8)];
        #pragma unroll
        for (int dt = 0; dt < 4; ++dt) {
            int vrow = dt * 16 + arow, sw = vrow & 7;
            bf16x8 vb0 = *(const bf16x8*)&Vs[vrow * 64 + ((kg ^ sw) * 8)];
            bf16x8 vb1 = *(const bf16x8*)&Vs[vrow * 64 + (((4 + kg) ^ sw) * 8)];
            po[dt] = __builtin_amdgcn_mfma_f32_16x16x32_bf16(pa[0], vb0, po[dt], 0, 0, 0);
            po[dt] = __builtin_amdgcn_mfma_f32_16x16x32_bf16(pa[1], vb1, po[dt], 0, 0, 0);
        }
        __syncthreads();
    }

    // epilogue: z[b][qrow][h*64 + d] = po / l
    const int b_ = bh >> 4, hofs = (bh & 15) * 64;
    #pragma unroll
    for (int dt = 0; dt < 4; ++dt)
        #pragma unroll
        for (int r = 0; r < 4; ++r) {
            long row = (long)b_ * 2048 + qb + w * 16 + kg * 4 + r;
            z[row * 1024 + hofs + dt * 16 + arow] = __float2bfloat16(po[dt][r] / lrow[r]);
        }
}

// ---------------- head ----------------
__global__ void head_kernel(const float* __restrict__ hl, const float* __restrict__ W,
                            float* __restrict__ out) {
    __shared__ float hs[2 * DMODEL];
    int tid = threadIdx.x;
    #pragma unroll
    for (int i = 0; i < 8; ++i) hs[tid + i * 256] = hl[tid + i * 256];
    __syncthreads();
    int v = blockIdx.x * 256 + tid;
    if (v >= VOCAB) return;
    float a0 = 0.f, a1 = 0.f;
    for (int d = 0; d < DMODEL; ++d) {
        float wv = W[(long)d * VOCAB + v];
        a0 += hs[d] * wv;
        a1 += hs[DMODEL + d] * wv;
    }
    out[v] = a0;
    out[VOCAB + v] = a1;
}

extern "C" void kernel_launch(void* const* d_in, const int* in_sizes, int n_in,
                              void* d_out, int out_size, void* d_ws, size_t ws_size,
                              hipStream_t stream) {
    const int*   x      = (const int*)  d_in[0];
    const float* wte    = (const float*)d_in[1];
    const float* wpe    = (const float*)d_in[2];
    const float* ln1_g  = (const float*)d_in[3];
    const float* ln1_b  = (const float*)d_in[4];
    const float* w_qkv  = (const float*)d_in[5];
    const float* b_qkv  = (const float*)d_in[6];
    const float* w_proj = (const float*)d_in[7];
    const float* b_proj = (const float*)d_in[8];
    const float* ln2_g  = (const float*)d_in[9];
    const float* ln2_b  = (const float*)d_in[10];
    const float* w_fc   = (const float*)d_in[11];
    const float* b_fc   = (const float*)d_in[12];
    const float* w_cp   = (const float*)d_in[13];
    const float* b_cp   = (const float*)d_in[14];
    const float* lnf_g  = (const float*)d_in[15];
    const float* lnf_b  = (const float*)d_in[16];
    const float* w_head = (const float*)d_in[17];
    float* out = (float*)d_out;

    char* ws = (char*)d_ws;
    float*          h     = (float*)ws;                             // 16 MB
    unsigned short* qkvB  = (unsigned short*)(ws + (16L << 20));    // qB|kB|vT, 24 MB
    __hip_bfloat16* y_bf  = (__hip_bfloat16*)(ws + (40L << 20));    // 8 MB
    __hip_bfloat16* z_bf  = (__hip_bfloat16*)(ws + (48L << 20));    // 8 MB
    __hip_bfloat16* fc_bf = (__hip_bfloat16*)(ws + (56L << 20));    // 32 MB
    __hip_bfloat16* wT    = (__hip_bfloat16*)(ws + (88L << 20));    // 8.5 MB
    float*          hl    = (float*)(ws + (97L << 20));             // 8 KB

    embed_kernel<<<NTOK, 256, 0, stream>>>(x, wte, wpe, h);

    for (int l = 0; l < NLAYER; ++l) {
        ln_kernel<__hip_bfloat16><<<NTOK, 256, 0, stream>>>(
            h, y_bf, ln1_g + l * DMODEL, ln1_b + l * DMODEL, DMODEL);

        convT_kernel<<<dim3(3072 / 32, 1024 / 32), 256, 0, stream>>>(
            w_qkv + (long)l * DMODEL * 3072, wT, 1024, 3072);
        mm_mfma<3><<<dim3(3072 / 128, NTOK / 128), 256, 0, stream>>>(
            (const unsigned short*)y_bf, (const unsigned short*)wT,
            b_qkv + l * 3072, nullptr, qkvB, NTOK, 3072, 1024);

        attn_mfma<<<dim3(BATCH * NHEAD, SEQ / 64), 256, 0, stream>>>(
            qkvB, qkvB + 4194304L, qkvB + 8388608L, z_bf);

        convT_kernel<<<dim3(1024 / 32, 1024 / 32), 256, 0, stream>>>(
            w_proj + (long)l * DMODEL * DMODEL, wT, 1024, 1024);
        mm_mfma<1><<<dim3(1024 / 128, NTOK / 128), 256, 0, stream>>>(
            (const unsigned short*)z_bf, (const unsigned short*)wT,
            b_proj + l * DMODEL, h, h, NTOK, 1024, 1024);

        ln_kernel<__hip_bfloat16><<<NTOK, 256, 0, stream>>>(
            h, y_bf, ln2_g + l * DMODEL, ln2_b + l * DMODEL, DMODEL);

        convT_kernel<<<dim3(4096 / 32, 1024 / 32), 256, 0, stream>>>(
            w_fc + (long)l * DMODEL * 4096, wT, 1024, 4096);
        mm_mfma<2><<<dim3(4096 / 128, NTOK / 128), 256, 0, stream>>>(
            (const unsigned short*)y_bf, (const unsigned short*)wT,
            b_fc + l * 4096, nullptr, fc_bf, NTOK, 4096, 1024);

        convT_kernel<<<dim3(1024 / 32, 4096 / 32), 256, 0, stream>>>(
            w_cp + (long)l * 4096 * DMODEL, wT, 4096, 1024);
        mm_mfma<1><<<dim3(1024 / 128, NTOK / 128), 256, 0, stream>>>(
            (const unsigned short*)fc_bf, (const unsigned short*)wT,
            b_cp + l * DMODEL, h, h, NTOK, 1024, 4096);
    }

    ln_kernel<float><<<BATCH, 256, 0, stream>>>(h + (long)(SEQ - 1) * DMODEL, hl,
                                                lnf_g, lnf_b, (long)SEQ * DMODEL);
    head_kernel<<<(VOCAB + 255) / 256, 256, 0, stream>>>(hl, w_head, out);
}